// Round 1
// baseline (58.218 us; speedup 1.0000x reference)
//
#include <hip/hip_runtime.h>
#include <math.h>

// Problem constants (from reference)
// N=1024 atoms, M=32 mols, NB=1024 bonds, NA=1536 angles, NT=2048 torsions, T=6, U=32
// atom->mol: e/32 (32/mol); bond->mol: e/32; angle->mol: e/48; torsion unused.
// masked-pair constant count per molecule: 32 * (1024-32) = 31744

__device__ __forceinline__ float sigmoidf_(float x) { return 1.0f / (1.0f + __expf(-x)); }

// ---------------------------------------------------------------------------
// Kernel 1: per-molecule 32x32 pair block. grid = 128 (4 blocks/mol), 256 thr.
// Writes partial[blockIdx][19] into d_ws (deterministic, no atomics).
// ---------------------------------------------------------------------------
__global__ __launch_bounds__(256) void pair_kernel(
    const float* __restrict__ h_v,      // [1024,32]
    const float* __restrict__ coords,   // [1024,3]
    const float* __restrict__ Wk, const float* __restrict__ bk,
    const float* __restrict__ Wq, const float* __restrict__ bq,
    const float* __restrict__ Wv0, const float* __restrict__ bv0,   // Wv0 [1,32]
    const float* __restrict__ Wv1, const float* __restrict__ bv1,   // Wv1 [32,32]
    const float* __restrict__ Wp0, const float* __restrict__ bp0,   // Wp0 [96,32]
    const float* __restrict__ Wp1, const float* __restrict__ bp1,   // Wp1 [32,19]
    float* __restrict__ partial)        // [128,19]
{
    __shared__ float Kl[32 * 33];   // +1 pad: kills 32-way bank conflict
    __shared__ float Ql[32 * 33];
    __shared__ float cxl[32], cyl[32], czl[32];
    __shared__ float wv0l[32], bv0l[32], bv1l[32], bp0l[32];
    __shared__ float wv1l[32 * 32];
    __shared__ float wp0l[96 * 32];
    __shared__ float wp1l[32 * 19];
    __shared__ float bp1l[19];
    __shared__ float redl[4 * 19];

    const int tid = threadIdx.x;
    const int b = blockIdx.x;
    const int m = b >> 2;        // molecule
    const int qq = b & 3;        // quarter of the 1024 pairs
    const int base = m * 32;     // first atom of molecule

    if (tid < 32) {
        wv0l[tid] = Wv0[tid]; bv0l[tid] = bv0[tid];
        bv1l[tid] = bv1[tid]; bp0l[tid] = bp0[tid];
        const int gi = base + tid;
        cxl[tid] = coords[gi * 3 + 0];
        cyl[tid] = coords[gi * 3 + 1];
        czl[tid] = coords[gi * 3 + 2];
    }
    if (tid < 19) bp1l[tid] = bp1[tid];
    for (int idx = tid; idx < 32 * 32; idx += 256) wv1l[idx] = Wv1[idx];
    for (int idx = tid; idx < 96 * 32; idx += 256) wp0l[idx] = Wp0[idx];
    for (int idx = tid; idx < 32 * 19; idx += 256) wp1l[idx] = Wp1[idx];

    // K,Q for this molecule's 32 atoms (redundant x4 blocks/mol; tiny)
    for (int idx = tid; idx < 1024; idx += 256) {
        const int il = idx >> 5, u = idx & 31;
        const float* hv = h_v + (size_t)(base + il) * 32;
        float sk = bk[u], sq = bq[u];
        #pragma unroll
        for (int t = 0; t < 32; ++t) {
            const float h = hv[t];
            sk += h * Wk[t * 32 + u];
            sq += h * Wq[t * 32 + u];
        }
        Kl[il * 33 + u] = sk;
        Ql[il * 33 + u] = sq;
    }
    __syncthreads();

    const int p = qq * 256 + tid;        // pair index in [0,1024)
    const int il = p >> 5;               // i_local (K side, summed axis)
    const int jl = p & 31;               // j_local (Q side)

    // distance
    const float dx = cxl[il] - cxl[jl];
    const float dy = cyl[il] - cyl[jl];
    const float dz = czl[il] - czl[jl];
    const float dist = sqrtf(fmaxf(dx * dx + dy * dy + dz * dz, 1e-12f));

    // V = elu(dist*Wv0 + bv0) @ Wv1 + bv1
    float ve[32];
    #pragma unroll
    for (int u = 0; u < 32; ++u) {
        const float x = dist * wv0l[u] + bv0l[u];
        ve[u] = (x > 0.0f) ? x : (__expf(x) - 1.0f);
    }
    float V[32];
    #pragma unroll
    for (int u = 0; u < 32; ++u) V[u] = bv1l[u];
    #pragma unroll
    for (int t = 0; t < 32; ++t) {
        const float a = ve[t];
        #pragma unroll
        for (int u = 0; u < 32; ++u) V[u] += a * wv1l[t * 32 + u];
    }

    // s = [K_i, Q_j, V] @ Wp0 + bp0
    float s[32];
    #pragma unroll
    for (int u = 0; u < 32; ++u) s[u] = bp0l[u];
    #pragma unroll
    for (int t = 0; t < 32; ++t) {
        const float a = Kl[il * 33 + t];
        #pragma unroll
        for (int u = 0; u < 32; ++u) s[u] += a * wp0l[t * 32 + u];
    }
    #pragma unroll
    for (int t = 0; t < 32; ++t) {
        const float a = Ql[jl * 33 + t];
        #pragma unroll
        for (int u = 0; u < 32; ++u) s[u] += a * wp0l[(32 + t) * 32 + u];
    }
    #pragma unroll
    for (int t = 0; t < 32; ++t) {
        const float a = V[t];
        #pragma unroll
        for (int u = 0; u < 32; ++u) s[u] += a * wp0l[(64 + t) * 32 + u];
    }

    // f = sigmoid(s) @ Wp1 + bp1  (bp1 per pair)
    float acc[19];
    #pragma unroll
    for (int c = 0; c < 19; ++c) acc[c] = bp1l[c];
    #pragma unroll
    for (int u = 0; u < 32; ++u) {
        const float g = sigmoidf_(s[u]);
        #pragma unroll
        for (int c = 0; c < 19; ++c) acc[c] += g * wp1l[u * 19 + c];
    }

    // block reduce: wave shuffle then cross-wave LDS
    #pragma unroll
    for (int c = 0; c < 19; ++c) {
        float v = acc[c];
        v += __shfl_down(v, 32);
        v += __shfl_down(v, 16);
        v += __shfl_down(v, 8);
        v += __shfl_down(v, 4);
        v += __shfl_down(v, 2);
        v += __shfl_down(v, 1);
        if ((tid & 63) == 0) redl[(tid >> 6) * 19 + c] = v;
    }
    __syncthreads();
    if (tid < 19)
        partial[b * 19 + tid] = redl[tid] + redl[19 + tid] + redl[38 + tid] + redl[57 + tid];
}

// ---------------------------------------------------------------------------
// Kernel 2: per-molecule segment sums + dense MLP + combine. grid = 32, 256 thr.
// ---------------------------------------------------------------------------
__global__ __launch_bounds__(256) void mol_kernel(
    const float* __restrict__ hvh,   // [1024,192]
    const float* __restrict__ heh,   // [1024,192]
    const float* __restrict__ hah,   // [1536,192]
    const float* __restrict__ huh,   // [32,192]
    const float* __restrict__ Wd0, const float* __restrict__ bd0,  // [960,64]
    const float* __restrict__ Wd1, const float* __restrict__ bd1,  // [64,64]
    const float* __restrict__ Wd2, const float* __restrict__ bd2,  // [64,19]
    const float* __restrict__ Wp1, const float* __restrict__ bp1,  // [32,19]
    const float* __restrict__ bp0,                                  // [32]
    const float* __restrict__ partial,                              // [128,19]
    float* __restrict__ out)                                        // [32,19]
{
    __shared__ float x[960];
    __shared__ float hp[4 * 64];
    __shared__ float h0[64];
    __shared__ float h1[64];

    const int tid = threadIdx.x;
    const int m = blockIdx.x;

    if (tid < 192) {
        float sv = 0.0f, se = 0.0f, sa = 0.0f;
        const float* pv = hvh + (size_t)(m * 32) * 192 + tid;
        const float* pe = heh + (size_t)(m * 32) * 192 + tid;
        const float* pa = hah + (size_t)(m * 48) * 192 + tid;
        for (int e = 0; e < 32; ++e) { sv += pv[e * 192]; se += pe[e * 192]; }
        for (int e = 0; e < 48; ++e) { sa += pa[e * 192]; }
        x[tid]       = sv;                 // h_v_bar
        x[192 + tid] = se;                 // h_e_bar
        x[384 + tid] = huh[m * 192 + tid]; // h_u_history
        x[576 + tid] = sa;                 // h_a_bar
        x[768 + tid] = sa;                 // h_a_bar again (per source)
    }
    __syncthreads();

    // hidden0: 960 -> 64, split across 4 partial groups
    {
        const int o = tid & 63, part = tid >> 6;
        float ssum = 0.0f;
        const int k0 = part * 240;
        for (int k = k0; k < k0 + 240; ++k) ssum += x[k] * Wd0[k * 64 + o];
        hp[part * 64 + o] = ssum;
    }
    __syncthreads();
    if (tid < 64)
        h0[tid] = sigmoidf_(hp[tid] + hp[64 + tid] + hp[128 + tid] + hp[192 + tid] + bd0[tid]);
    __syncthreads();
    if (tid < 64) {
        float ssum = bd1[tid];
        #pragma unroll
        for (int k = 0; k < 64; ++k) ssum += h0[k] * Wd1[k * 64 + tid];
        h1[tid] = ssum;
    }
    __syncthreads();
    if (tid < 19) {
        float y = bd2[tid];
        for (int k = 0; k < 64; ++k) y += h1[k] * Wd2[k * 19 + tid];
        // constant contribution of masked pairs: c0 = sigmoid(bp0) @ Wp1 + bp1
        float c0 = bp1[tid];
        for (int u = 0; u < 32; ++u) c0 += sigmoidf_(bp0[u]) * Wp1[u * 19 + tid];
        const float pr = partial[(4 * m + 0) * 19 + tid]
                       + partial[(4 * m + 1) * 19 + tid]
                       + partial[(4 * m + 2) * 19 + tid]
                       + partial[(4 * m + 3) * 19 + tid];
        out[m * 19 + tid] = y + pr + 31744.0f * c0;
    }
}

extern "C" void kernel_launch(void* const* d_in, const int* in_sizes, int n_in,
                              void* d_out, int out_size, void* d_ws, size_t ws_size,
                              hipStream_t stream) {
    (void)in_sizes; (void)n_in; (void)out_size; (void)ws_size;
    const float* h_v    = (const float*)d_in[0];
    const float* hvh    = (const float*)d_in[5];
    const float* heh    = (const float*)d_in[6];
    const float* hah    = (const float*)d_in[7];
    const float* huh    = (const float*)d_in[9];
    const float* coords = (const float*)d_in[15];
    const float* Wk  = (const float*)d_in[16]; const float* bk  = (const float*)d_in[17];
    const float* Wq  = (const float*)d_in[18]; const float* bq  = (const float*)d_in[19];
    const float* Wv0 = (const float*)d_in[20]; const float* bv0 = (const float*)d_in[21];
    const float* Wv1 = (const float*)d_in[22]; const float* bv1 = (const float*)d_in[23];
    const float* Wp0 = (const float*)d_in[24]; const float* bp0 = (const float*)d_in[25];
    const float* Wp1 = (const float*)d_in[26]; const float* bp1 = (const float*)d_in[27];
    const float* Wd0 = (const float*)d_in[28]; const float* bd0 = (const float*)d_in[29];
    const float* Wd1 = (const float*)d_in[30]; const float* bd1 = (const float*)d_in[31];
    const float* Wd2 = (const float*)d_in[32]; const float* bd2 = (const float*)d_in[33];

    float* partial = (float*)d_ws;   // [128,19] floats = 9728 B

    pair_kernel<<<128, 256, 0, stream>>>(h_v, coords, Wk, bk, Wq, bq,
                                         Wv0, bv0, Wv1, bv1, Wp0, bp0, Wp1, bp1,
                                         partial);
    mol_kernel<<<32, 256, 0, stream>>>(hvh, heh, hah, huh,
                                       Wd0, bd0, Wd1, bd1, Wd2, bd2,
                                       Wp1, bp1, bp0, partial, (float*)d_out);
}

// Round 3
// 35.327 us; speedup vs baseline: 1.6480x; 1.6480x over previous
//
#include <hip/hip_runtime.h>
#include <math.h>

// N=1024 atoms, M=32 mols, NB=1024 bonds, NA=1536 angles, T=6, U=32
// atom->mol e/32 (32/mol), bond->mol e/32, angle->mol e/48; torsion unused.
// Masked pairs per mol: 32*(1024-32) = 31744; real in-mol pairs: 1024/mol.
// s_pair = K_i@Wp0_k + Q_j@Wp0_q + elu(d*Wv0+bv0)@(Wv1@Wp0_v) + (bv1@Wp0_v + bp0)

__device__ __forceinline__ float sigmoidf_(float x) { return 1.0f / (1.0f + __expf(-x)); }

// ---------------------------------------------------------------------------
// Pair kernel: 128 blocks x 256 threads. Block b: mol = b>>2, quarter = b&3,
// 256 pairs, 1 pair/thread, full 32 s-channels in registers.
// Per-block prep (redundant x4/mol): K,Q -> SK,SQ; W2; cb. ~640 MACs/thread.
// Output: partial[b][19] (deterministic, no atomics). ws needs 128*19 floats.
// ---------------------------------------------------------------------------
__global__ __launch_bounds__(256) void pair_kernel(
    const float* __restrict__ h_v,      // [1024,32]
    const float* __restrict__ coords,   // [1024,3]
    const float* __restrict__ Wk, const float* __restrict__ bk,
    const float* __restrict__ Wq, const float* __restrict__ bq,
    const float* __restrict__ Wv0, const float* __restrict__ bv0,   // [32],[32]
    const float* __restrict__ Wv1, const float* __restrict__ bv1,   // [32,32],[32]
    const float* __restrict__ Wp0, const float* __restrict__ bp0,   // [96,32],[32]
    const float* __restrict__ Wp1,                                  // [32,19]
    float* __restrict__ partial)        // [128,19]
{
    __shared__ float hl[1024];          // h_v rows of this mol
    __shared__ float wkl[1024], wql[1024];
    __shared__ float wp0l[3072];        // all of Wp0
    __shared__ float wv1l[1024];
    __shared__ float Kl[32 * 33], Ql[32 * 33];
    __shared__ float SKl[32 * 33], SQl[32 * 33];
    __shared__ float W2l[1024];
    __shared__ float wp1l[608];
    __shared__ float cbl[32], wv0l[32], bv0l[32];
    __shared__ float cxl[32], cyl[32], czl[32];
    __shared__ float Gl[4 * 32];
    __shared__ float Gs[32];

    const int tid = threadIdx.x;
    const int b = blockIdx.x;
    const int mol = b >> 2;
    const int qq = b & 3;
    const int base = mol * 32;

    // ---- stage everything (strided/vector loads; no partial-load bugs) ----
    ((float4*)hl)[tid]   = ((const float4*)(h_v + (size_t)base * 32))[tid];
    ((float4*)wkl)[tid]  = ((const float4*)Wk)[tid];
    ((float4*)wql)[tid]  = ((const float4*)Wq)[tid];
    ((float4*)wv1l)[tid] = ((const float4*)Wv1)[tid];
    ((float4*)wp0l)[tid]       = ((const float4*)Wp0)[tid];
    ((float4*)wp0l)[tid + 256] = ((const float4*)Wp0)[tid + 256];
    ((float4*)wp0l)[tid + 512] = ((const float4*)Wp0)[tid + 512];
    for (int i = tid; i < 608; i += 256) wp1l[i] = Wp1[i];
    if (tid < 32) {
        wv0l[tid] = Wv0[tid];
        bv0l[tid] = bv0[tid];
        const int gi = base + tid;
        cxl[tid] = coords[gi * 3 + 0];
        cyl[tid] = coords[gi * 3 + 1];
        czl[tid] = coords[gi * 3 + 2];
    }
    __syncthreads();

    // ---- prep 1: K = h@Wk+bk, Q = h@Wq+bq (stride-33 tiles) ----
    #pragma unroll
    for (int it = 0; it < 4; ++it) {
        const int idx = tid + it * 256;
        const int a = idx >> 5, u = idx & 31;
        float sk = bk[u], sq = bq[u];
        #pragma unroll
        for (int t = 0; t < 32; ++t) {
            const float h = hl[a * 32 + t];
            sk += h * wkl[t * 32 + u];
            sq += h * wql[t * 32 + u];
        }
        Kl[a * 33 + u] = sk;
        Ql[a * 33 + u] = sq;
    }
    __syncthreads();

    // ---- prep 2: SK = K@Wp0_k, SQ = Q@Wp0_q, W2 = Wv1@Wp0_v, cb ----
    #pragma unroll
    for (int it = 0; it < 4; ++it) {
        const int idx = tid + it * 256;
        const int a = idx >> 5, w = idx & 31;
        float s1 = 0.0f, s2 = 0.0f, s3 = 0.0f;
        #pragma unroll
        for (int u = 0; u < 32; ++u) {
            s1 += Kl[a * 33 + u]   * wp0l[u * 32 + w];
            s2 += Ql[a * 33 + u]   * wp0l[(32 + u) * 32 + w];
            s3 += wv1l[a * 32 + u] * wp0l[(64 + u) * 32 + w];
        }
        SKl[a * 33 + w] = s1;
        SQl[a * 33 + w] = s2;
        W2l[a * 32 + w] = s3;
    }
    if (tid < 32) {
        float s = bp0[tid];
        #pragma unroll
        for (int u = 0; u < 32; ++u) s += bv1[u] * wp0l[(64 + u) * 32 + tid];
        cbl[tid] = s;
    }
    __syncthreads();

    // ---- pair phase: p in [0,1024) of this mol ----
    const int p = qq * 256 + tid;
    const int il = p >> 5;               // K side (summed axis i)
    const int jl = p & 31;               // Q side (output axis j)

    const float dx = cxl[il] - cxl[jl];
    const float dy = cyl[il] - cyl[jl];
    const float dz = czl[il] - czl[jl];
    const float dist = sqrtf(fmaxf(dx * dx + dy * dy + dz * dz, 1e-12f));

    float e[32];
    #pragma unroll
    for (int t = 0; t < 32; ++t) {
        const float x = dist * wv0l[t] + bv0l[t];
        e[t] = (x > 0.0f) ? x : (__expf(x) - 1.0f);
    }

    float s[32];
    #pragma unroll
    for (int k = 0; k < 32; ++k)
        s[k] = SKl[il * 33 + k] + SQl[jl * 33 + k] + cbl[k];
    #pragma unroll
    for (int t = 0; t < 32; ++t) {
        const float a = e[t];
        #pragma unroll
        for (int k = 0; k < 32; ++k) s[k] += a * W2l[t * 32 + k];
    }

    // g = sigmoid(s); sum over all pairs BEFORE the Wp1 matvec (linearity)
    #pragma unroll
    for (int k = 0; k < 32; ++k) {
        float v = sigmoidf_(s[k]);
        v += __shfl_xor(v, 1);
        v += __shfl_xor(v, 2);
        v += __shfl_xor(v, 4);
        v += __shfl_xor(v, 8);
        v += __shfl_xor(v, 16);
        v += __shfl_xor(v, 32);
        s[k] = v;                         // wave total, same on all lanes
    }
    const int lane = tid & 63, wid = tid >> 6;
    if (lane == 0) {
        #pragma unroll
        for (int k = 0; k < 32; ++k) Gl[wid * 32 + k] = s[k];
    }
    __syncthreads();
    if (tid < 32) Gs[tid] = Gl[tid] + Gl[32 + tid] + Gl[64 + tid] + Gl[96 + tid];
    __syncthreads();
    if (tid < 19) {
        float r = 0.0f;
        #pragma unroll
        for (int u = 0; u < 32; ++u) r += Gs[u] * wp1l[u * 19 + tid];
        partial[b * 19 + tid] = r;
    }
}

// ---------------------------------------------------------------------------
// Mol kernel: segment sums + 960->64->64->19 MLP + combine. 32 blocks x 256.
// ---------------------------------------------------------------------------
__global__ __launch_bounds__(256) void mol_kernel(
    const float* __restrict__ hvh,   // [1024,192]
    const float* __restrict__ heh,   // [1024,192]
    const float* __restrict__ hah,   // [1536,192]
    const float* __restrict__ huh,   // [32,192]
    const float* __restrict__ Wd0, const float* __restrict__ bd0,  // [960,64]
    const float* __restrict__ Wd1, const float* __restrict__ bd1,  // [64,64]
    const float* __restrict__ Wd2, const float* __restrict__ bd2,  // [64,19]
    const float* __restrict__ Wp1, const float* __restrict__ bp1,  // [32,19]
    const float* __restrict__ bp0,                                  // [32]
    const float* __restrict__ partial,                              // [128,19]
    float* __restrict__ out)                                        // [32,19]
{
    __shared__ float xv[4][192], xe[4][192], xa[4][192];
    __shared__ float x[960];
    __shared__ float hp[4 * 64];
    __shared__ float h0[64];
    __shared__ float h1[64];

    const int tid = threadIdx.x;
    const int m = blockIdx.x;
    const int c4 = tid >> 2, sub = tid & 3;

    if (c4 < 48) {
        float4 sv = {0, 0, 0, 0}, se = {0, 0, 0, 0}, sa = {0, 0, 0, 0};
        const float* pv = hvh + (size_t)(m * 32) * 192;
        const float* pe = heh + (size_t)(m * 32) * 192;
        const float* pa = hah + (size_t)(m * 48) * 192;
        for (int e = sub; e < 32; e += 4) {
            const float4 a = *(const float4*)(pv + e * 192 + c4 * 4);
            const float4 bq = *(const float4*)(pe + e * 192 + c4 * 4);
            sv.x += a.x; sv.y += a.y; sv.z += a.z; sv.w += a.w;
            se.x += bq.x; se.y += bq.y; se.z += bq.z; se.w += bq.w;
        }
        for (int e = sub; e < 48; e += 4) {
            const float4 a = *(const float4*)(pa + e * 192 + c4 * 4);
            sa.x += a.x; sa.y += a.y; sa.z += a.z; sa.w += a.w;
        }
        xv[sub][c4 * 4 + 0] = sv.x; xv[sub][c4 * 4 + 1] = sv.y;
        xv[sub][c4 * 4 + 2] = sv.z; xv[sub][c4 * 4 + 3] = sv.w;
        xe[sub][c4 * 4 + 0] = se.x; xe[sub][c4 * 4 + 1] = se.y;
        xe[sub][c4 * 4 + 2] = se.z; xe[sub][c4 * 4 + 3] = se.w;
        xa[sub][c4 * 4 + 0] = sa.x; xa[sub][c4 * 4 + 1] = sa.y;
        xa[sub][c4 * 4 + 2] = sa.z; xa[sub][c4 * 4 + 3] = sa.w;
    }
    __syncthreads();
    if (tid < 192) {
        const float sv = xv[0][tid] + xv[1][tid] + xv[2][tid] + xv[3][tid];
        const float se = xe[0][tid] + xe[1][tid] + xe[2][tid] + xe[3][tid];
        const float sa = xa[0][tid] + xa[1][tid] + xa[2][tid] + xa[3][tid];
        x[tid]       = sv;                 // h_v_bar
        x[192 + tid] = se;                 // h_e_bar
        x[384 + tid] = huh[m * 192 + tid]; // h_u_history
        x[576 + tid] = sa;                 // h_a_bar
        x[768 + tid] = sa;                 // h_a_bar again (per source)
    }
    __syncthreads();

    {
        const int o = tid & 63, part = tid >> 6;
        float ssum = 0.0f;
        const int k0 = part * 240;
        for (int k = k0; k < k0 + 240; ++k) ssum += x[k] * Wd0[k * 64 + o];
        hp[part * 64 + o] = ssum;
    }
    __syncthreads();
    if (tid < 64)
        h0[tid] = sigmoidf_(hp[tid] + hp[64 + tid] + hp[128 + tid] + hp[192 + tid] + bd0[tid]);
    __syncthreads();
    if (tid < 64) {
        float ssum = bd1[tid];
        #pragma unroll
        for (int k = 0; k < 64; ++k) ssum += h0[k] * Wd1[k * 64 + tid];
        h1[tid] = ssum;
    }
    __syncthreads();
    if (tid < 19) {
        float y = bd2[tid];
        for (int k = 0; k < 64; ++k) y += h1[k] * Wd2[k * 19 + tid];
        // masked pairs: 31744*(sigmoid(bp0)@Wp1); bp1 appears 32768x total
        float c0m = 0.0f;
        for (int u = 0; u < 32; ++u) c0m += sigmoidf_(bp0[u]) * Wp1[u * 19 + tid];
        const float pr = partial[(4 * m + 0) * 19 + tid]
                       + partial[(4 * m + 1) * 19 + tid]
                       + partial[(4 * m + 2) * 19 + tid]
                       + partial[(4 * m + 3) * 19 + tid];
        out[m * 19 + tid] = y + pr + 31744.0f * c0m + 32768.0f * bp1[tid];
    }
}

extern "C" void kernel_launch(void* const* d_in, const int* in_sizes, int n_in,
                              void* d_out, int out_size, void* d_ws, size_t ws_size,
                              hipStream_t stream) {
    (void)in_sizes; (void)n_in; (void)out_size; (void)ws_size;
    const float* h_v    = (const float*)d_in[0];
    const float* hvh    = (const float*)d_in[5];
    const float* heh    = (const float*)d_in[6];
    const float* hah    = (const float*)d_in[7];
    const float* huh    = (const float*)d_in[9];
    const float* coords = (const float*)d_in[15];
    const float* Wk  = (const float*)d_in[16]; const float* bk  = (const float*)d_in[17];
    const float* Wq  = (const float*)d_in[18]; const float* bq  = (const float*)d_in[19];
    const float* Wv0 = (const float*)d_in[20]; const float* bv0 = (const float*)d_in[21];
    const float* Wv1 = (const float*)d_in[22]; const float* bv1 = (const float*)d_in[23];
    const float* Wp0 = (const float*)d_in[24]; const float* bp0 = (const float*)d_in[25];
    const float* Wp1 = (const float*)d_in[26]; const float* bp1 = (const float*)d_in[27];
    const float* Wd0 = (const float*)d_in[28]; const float* bd0 = (const float*)d_in[29];
    const float* Wd1 = (const float*)d_in[30]; const float* bd1 = (const float*)d_in[31];
    const float* Wd2 = (const float*)d_in[32]; const float* bd2 = (const float*)d_in[33];

    float* partial = (float*)d_ws;   // [128,19] floats = 9728 B (same as round 1)

    pair_kernel<<<128, 256, 0, stream>>>(h_v, coords, Wk, bk, Wq, bq,
                                         Wv0, bv0, Wv1, bv1, Wp0, bp0, Wp1,
                                         partial);
    mol_kernel<<<32, 256, 0, stream>>>(hvh, heh, hah, huh,
                                       Wd0, bd0, Wd1, bd1, Wd2, bd2,
                                       Wp1, bp1, bp0, partial, (float*)d_out);
}

// Round 4
// 23.417 us; speedup vs baseline: 2.4861x; 1.5086x over previous
//
#include <hip/hip_runtime.h>
#include <math.h>

// N=1024 atoms, M=32 mols, NB=1024 bonds, NA=1536 angles, T=6, U=32
// atom->mol e/32 (32/mol), bond->mol e/32, angle->mol e/48; torsion unused.
// Masked pairs per mol: 32*(1024-32)=31744; real in-mol pairs: 1024/mol.
// s_pair = SK[i] + SQ[j] + elu(d*Wv0+bv0)@W2 + cb
//   SK = (h@Wk+bk)@Wp0_k, SQ = (h@Wq+bq)@Wp0_q, W2 = Wv1@Wp0_v, cb = bv1@Wp0_v + bp0
// Output per block: partial[b][19] = (sum of sigmoid(s) over block pairs) @ Wp1

__device__ __forceinline__ float sigmoidf_(float x) { return 1.0f / (1.0f + __expf(-x)); }

// ---------------------------------------------------------------------------
// Pair kernel: 256 blocks x 256 threads. Block b: mol=b>>3, oct=b&7,
// 128 pairs; 4 threads/pair x 8 channels, 2 pairs/thread (same K-row).
// ---------------------------------------------------------------------------
__global__ __launch_bounds__(256) void pair_kernel(
    const float* __restrict__ h_v,      // [1024,32]
    const float* __restrict__ coords,   // [1024,3]
    const float* __restrict__ Wk, const float* __restrict__ bk,
    const float* __restrict__ Wq, const float* __restrict__ bq,
    const float* __restrict__ Wv0, const float* __restrict__ bv0,   // [32],[32]
    const float* __restrict__ Wv1, const float* __restrict__ bv1,   // [32,32],[32]
    const float* __restrict__ Wp0, const float* __restrict__ bp0,   // [96,32],[32]
    const float* __restrict__ Wp1,                                  // [32,19]
    float* __restrict__ partial)        // [256,19]
{
    __shared__ float hl[1024];
    __shared__ float wkl[1024], wql[1024], wv1l[1024];
    __shared__ float wp0l[3072];
    __shared__ float Kl[32 * 36], Ql[32 * 36];       // pad 36: 16B-aligned rows
    __shared__ float SKl[32 * 36], SQl[32 * 36];
    __shared__ float W2l[1024];
    __shared__ float wp1l[608];
    __shared__ float cbl[32], wv0l[32], bv0l[32];
    __shared__ float cxl[32], cyl[32], czl[32];
    __shared__ float Gl[4 * 32];
    __shared__ float Gs[32];

    const int tid = threadIdx.x;
    const int b = blockIdx.x;
    const int mol = b >> 3;
    const int oct = b & 7;
    const int base = mol * 32;

    // ---- stage ----
    ((float4*)hl)[tid]   = ((const float4*)(h_v + (size_t)base * 32))[tid];
    ((float4*)wkl)[tid]  = ((const float4*)Wk)[tid];
    ((float4*)wql)[tid]  = ((const float4*)Wq)[tid];
    ((float4*)wv1l)[tid] = ((const float4*)Wv1)[tid];
    ((float4*)wp0l)[tid]       = ((const float4*)Wp0)[tid];
    ((float4*)wp0l)[tid + 256] = ((const float4*)Wp0)[tid + 256];
    ((float4*)wp0l)[tid + 512] = ((const float4*)Wp0)[tid + 512];
    for (int i = tid; i < 608; i += 256) wp1l[i] = Wp1[i];
    if (tid < 32) {
        wv0l[tid] = Wv0[tid];
        bv0l[tid] = bv0[tid];
        const int gi = base + tid;
        cxl[tid] = coords[gi * 3 + 0];
        cyl[tid] = coords[gi * 3 + 1];
        czl[tid] = coords[gi * 3 + 2];
    }
    __syncthreads();

    // ---- P1: K = h@Wk+bk, Q = h@Wq+bq. 4 rows/thread, reg-tiled ----
    {
        const int u = tid & 31, g = tid >> 5;       // g in [0,8): rows g*4..g*4+3
        const int a0 = g * 4;
        float ka[4], qa[4];
        #pragma unroll
        for (int j = 0; j < 4; ++j) { ka[j] = bk[u]; qa[j] = bq[u]; }
        #pragma unroll
        for (int t4 = 0; t4 < 32; t4 += 4) {
            float4 h0 = *(const float4*)&hl[(a0 + 0) * 32 + t4];
            float4 h1 = *(const float4*)&hl[(a0 + 1) * 32 + t4];
            float4 h2 = *(const float4*)&hl[(a0 + 2) * 32 + t4];
            float4 h3 = *(const float4*)&hl[(a0 + 3) * 32 + t4];
            #pragma unroll
            for (int i = 0; i < 4; ++i) {
                const float wk = wkl[(t4 + i) * 32 + u];
                const float wq = wql[(t4 + i) * 32 + u];
                const float e0 = (&h0.x)[i], e1 = (&h1.x)[i], e2 = (&h2.x)[i], e3 = (&h3.x)[i];
                ka[0] += e0 * wk; ka[1] += e1 * wk; ka[2] += e2 * wk; ka[3] += e3 * wk;
                qa[0] += e0 * wq; qa[1] += e1 * wq; qa[2] += e2 * wq; qa[3] += e3 * wq;
            }
        }
        #pragma unroll
        for (int j = 0; j < 4; ++j) {
            Kl[(a0 + j) * 36 + u] = ka[j];
            Ql[(a0 + j) * 36 + u] = qa[j];
        }
    }
    __syncthreads();

    // ---- P2: SK = K@Wp0_k, SQ = Q@Wp0_q, W2 = Wv1@Wp0_v, cb ----
    {
        const int w = tid & 31, g = tid >> 5;
        const int a0 = g * 4;
        float sk[4] = {0, 0, 0, 0}, sq[4] = {0, 0, 0, 0}, w2[4] = {0, 0, 0, 0};
        #pragma unroll
        for (int u4 = 0; u4 < 32; u4 += 4) {
            float4 k0 = *(const float4*)&Kl[(a0 + 0) * 36 + u4];
            float4 k1 = *(const float4*)&Kl[(a0 + 1) * 36 + u4];
            float4 k2 = *(const float4*)&Kl[(a0 + 2) * 36 + u4];
            float4 k3 = *(const float4*)&Kl[(a0 + 3) * 36 + u4];
            float4 q0 = *(const float4*)&Ql[(a0 + 0) * 36 + u4];
            float4 q1 = *(const float4*)&Ql[(a0 + 1) * 36 + u4];
            float4 q2 = *(const float4*)&Ql[(a0 + 2) * 36 + u4];
            float4 q3 = *(const float4*)&Ql[(a0 + 3) * 36 + u4];
            float4 v0 = *(const float4*)&wv1l[(a0 + 0) * 32 + u4];
            float4 v1 = *(const float4*)&wv1l[(a0 + 1) * 32 + u4];
            float4 v2 = *(const float4*)&wv1l[(a0 + 2) * 32 + u4];
            float4 v3 = *(const float4*)&wv1l[(a0 + 3) * 32 + u4];
            #pragma unroll
            for (int i = 0; i < 4; ++i) {
                const float pk = wp0l[(u4 + i) * 32 + w];
                const float pq = wp0l[(32 + u4 + i) * 32 + w];
                const float pv = wp0l[(64 + u4 + i) * 32 + w];
                sk[0] += (&k0.x)[i] * pk; sk[1] += (&k1.x)[i] * pk;
                sk[2] += (&k2.x)[i] * pk; sk[3] += (&k3.x)[i] * pk;
                sq[0] += (&q0.x)[i] * pq; sq[1] += (&q1.x)[i] * pq;
                sq[2] += (&q2.x)[i] * pq; sq[3] += (&q3.x)[i] * pq;
                w2[0] += (&v0.x)[i] * pv; w2[1] += (&v1.x)[i] * pv;
                w2[2] += (&v2.x)[i] * pv; w2[3] += (&v3.x)[i] * pv;
            }
        }
        #pragma unroll
        for (int j = 0; j < 4; ++j) {
            SKl[(a0 + j) * 36 + w] = sk[j];
            SQl[(a0 + j) * 36 + w] = sq[j];
            W2l[(a0 + j) * 32 + w] = w2[j];
        }
    }
    if (tid < 32) {
        float s = bp0[tid];
        #pragma unroll
        for (int u = 0; u < 32; ++u) s += bv1[u] * wp0l[(64 + u) * 32 + tid];
        cbl[tid] = s;
    }
    __syncthreads();

    // ---- P3: pairs. ps=tid>>2 in [0,64), sub=tid&3; 2 pairs, same K-row ----
    const int ps = tid >> 2, sub = tid & 3;
    const int p0 = oct * 128 + ps * 2;           // even -> jl1 = jl0+1, same il
    const int il = p0 >> 5;
    const int jl0 = p0 & 31, jl1 = jl0 + 1;

    const float cix = cxl[il], ciy = cyl[il], ciz = czl[il];
    const float dx0 = cix - cxl[jl0], dy0 = ciy - cyl[jl0], dz0 = ciz - czl[jl0];
    const float dx1 = cix - cxl[jl1], dy1 = ciy - cyl[jl1], dz1 = ciz - czl[jl1];
    const float dist0 = sqrtf(fmaxf(dx0 * dx0 + dy0 * dy0 + dz0 * dz0, 1e-12f));
    const float dist1 = sqrtf(fmaxf(dx1 * dx1 + dy1 * dy1 + dz1 * dz1, 1e-12f));

    float e0[32], e1[32];
    #pragma unroll
    for (int t = 0; t < 32; ++t) {
        const float x0 = dist0 * wv0l[t] + bv0l[t];
        const float x1 = dist1 * wv0l[t] + bv0l[t];
        e0[t] = (x0 > 0.0f) ? x0 : (__expf(x0) - 1.0f);
        e1[t] = (x1 > 0.0f) ? x1 : (__expf(x1) - 1.0f);
    }

    float s0[8], s1[8];
    {
        const float4 ska = *(const float4*)&SKl[il * 36 + sub * 8];
        const float4 skb = *(const float4*)&SKl[il * 36 + sub * 8 + 4];
        const float4 cba = *(const float4*)&cbl[sub * 8];
        const float4 cbb = *(const float4*)&cbl[sub * 8 + 4];
        const float4 q0a = *(const float4*)&SQl[jl0 * 36 + sub * 8];
        const float4 q0b = *(const float4*)&SQl[jl0 * 36 + sub * 8 + 4];
        const float4 q1a = *(const float4*)&SQl[jl1 * 36 + sub * 8];
        const float4 q1b = *(const float4*)&SQl[jl1 * 36 + sub * 8 + 4];
        #pragma unroll
        for (int i = 0; i < 4; ++i) {
            s0[i]     = (&ska.x)[i] + (&q0a.x)[i] + (&cba.x)[i];
            s0[i + 4] = (&skb.x)[i] + (&q0b.x)[i] + (&cbb.x)[i];
            s1[i]     = (&ska.x)[i] + (&q1a.x)[i] + (&cba.x)[i];
            s1[i + 4] = (&skb.x)[i] + (&q1b.x)[i] + (&cbb.x)[i];
        }
    }
    #pragma unroll
    for (int t = 0; t < 32; ++t) {
        const float4 wa = *(const float4*)&W2l[t * 32 + sub * 8];
        const float4 wb = *(const float4*)&W2l[t * 32 + sub * 8 + 4];
        const float a0 = e0[t], a1 = e1[t];
        #pragma unroll
        for (int i = 0; i < 4; ++i) {
            s0[i]     += a0 * (&wa.x)[i];
            s0[i + 4] += a0 * (&wb.x)[i];
            s1[i]     += a1 * (&wa.x)[i];
            s1[i + 4] += a1 * (&wb.x)[i];
        }
    }

    // g = sigmoid over both pairs; reduce over the wave's 16 pair-slots
    float g[8];
    #pragma unroll
    for (int k = 0; k < 8; ++k) g[k] = sigmoidf_(s0[k]) + sigmoidf_(s1[k]);
    #pragma unroll
    for (int k = 0; k < 8; ++k) {
        g[k] += __shfl_xor(g[k], 4);
        g[k] += __shfl_xor(g[k], 8);
        g[k] += __shfl_xor(g[k], 16);
        g[k] += __shfl_xor(g[k], 32);
    }
    const int lane = tid & 63, wid = tid >> 6;
    if (lane < 4) {
        #pragma unroll
        for (int k = 0; k < 8; ++k) Gl[wid * 32 + sub * 8 + k] = g[k];
    }
    __syncthreads();
    if (tid < 32) Gs[tid] = Gl[tid] + Gl[32 + tid] + Gl[64 + tid] + Gl[96 + tid];
    __syncthreads();
    if (tid < 19) {
        float r = 0.0f;
        #pragma unroll
        for (int u = 0; u < 32; ++u) r += Gs[u] * wp1l[u * 19 + tid];
        partial[b * 19 + tid] = r;
    }
}

// ---------------------------------------------------------------------------
// Mol kernel: segment sums + 960->64->64->19 MLP + combine. 32 blocks x 512.
// ---------------------------------------------------------------------------
__global__ __launch_bounds__(512) void mol_kernel(
    const float* __restrict__ hvh,   // [1024,192]
    const float* __restrict__ heh,   // [1024,192]
    const float* __restrict__ hah,   // [1536,192]
    const float* __restrict__ huh,   // [32,192]
    const float* __restrict__ Wd0, const float* __restrict__ bd0,  // [960,64]
    const float* __restrict__ Wd1, const float* __restrict__ bd1,  // [64,64]
    const float* __restrict__ Wd2, const float* __restrict__ bd2,  // [64,19]
    const float* __restrict__ Wp1, const float* __restrict__ bp1,  // [32,19]
    const float* __restrict__ bp0,                                  // [32]
    const float* __restrict__ partial,                              // [256,19]
    float* __restrict__ out)                                        // [32,19]
{
    __shared__ float xv[2][192], xe[2][192], xa[2][192];
    __shared__ float x[960];
    __shared__ float hp[8 * 64];
    __shared__ float h0[64];
    __shared__ float h1[64];

    const int tid = threadIdx.x;
    const int m = blockIdx.x;

    if (tid < 384) {
        const int col = tid % 192, eg = tid / 192;   // 2-way entity split
        float sv = 0.0f, se = 0.0f, sa = 0.0f;
        const float* pv = hvh + (size_t)(m * 32) * 192 + col;
        const float* pe = heh + (size_t)(m * 32) * 192 + col;
        const float* pa = hah + (size_t)(m * 48) * 192 + col;
        for (int e = eg * 16; e < eg * 16 + 16; ++e) {
            sv += pv[e * 192];
            se += pe[e * 192];
        }
        for (int e = eg * 24; e < eg * 24 + 24; ++e) sa += pa[e * 192];
        xv[eg][col] = sv; xe[eg][col] = se; xa[eg][col] = sa;
    }
    __syncthreads();
    if (tid < 192) {
        const float sv = xv[0][tid] + xv[1][tid];
        const float se = xe[0][tid] + xe[1][tid];
        const float sa = xa[0][tid] + xa[1][tid];
        x[tid]       = sv;                 // h_v_bar
        x[192 + tid] = se;                 // h_e_bar
        x[384 + tid] = huh[m * 192 + tid]; // h_u_history
        x[576 + tid] = sa;                 // h_a_bar
        x[768 + tid] = sa;                 // h_a_bar again (per source)
    }
    __syncthreads();

    {
        const int o = tid & 63, part = tid >> 6;     // 8-way k split
        float ssum = 0.0f;
        const int k0 = part * 120;
        #pragma unroll 4
        for (int k = k0; k < k0 + 120; ++k) ssum += x[k] * Wd0[k * 64 + o];
        hp[part * 64 + o] = ssum;
    }
    __syncthreads();
    if (tid < 64) {
        float v = bd0[tid];
        #pragma unroll
        for (int p = 0; p < 8; ++p) v += hp[p * 64 + tid];
        h0[tid] = sigmoidf_(v);
    }
    __syncthreads();
    if (tid < 64) {
        float ssum = bd1[tid];
        #pragma unroll
        for (int k = 0; k < 64; ++k) ssum += h0[k] * Wd1[k * 64 + tid];
        h1[tid] = ssum;
    }
    __syncthreads();
    if (tid < 19) {
        float y = bd2[tid];
        for (int k = 0; k < 64; ++k) y += h1[k] * Wd2[k * 19 + tid];
        // masked pairs: 31744*(sigmoid(bp0)@Wp1); bp1 appears 32768x total
        float c0m = 0.0f;
        for (int u = 0; u < 32; ++u) c0m += sigmoidf_(bp0[u]) * Wp1[u * 19 + tid];
        float pr = 0.0f;
        #pragma unroll
        for (int t = 0; t < 8; ++t) pr += partial[(m * 8 + t) * 19 + tid];
        out[m * 19 + tid] = y + pr + 31744.0f * c0m + 32768.0f * bp1[tid];
    }
}

extern "C" void kernel_launch(void* const* d_in, const int* in_sizes, int n_in,
                              void* d_out, int out_size, void* d_ws, size_t ws_size,
                              hipStream_t stream) {
    (void)in_sizes; (void)n_in; (void)out_size; (void)ws_size;
    const float* h_v    = (const float*)d_in[0];
    const float* hvh    = (const float*)d_in[5];
    const float* heh    = (const float*)d_in[6];
    const float* hah    = (const float*)d_in[7];
    const float* huh    = (const float*)d_in[9];
    const float* coords = (const float*)d_in[15];
    const float* Wk  = (const float*)d_in[16]; const float* bk  = (const float*)d_in[17];
    const float* Wq  = (const float*)d_in[18]; const float* bq  = (const float*)d_in[19];
    const float* Wv0 = (const float*)d_in[20]; const float* bv0 = (const float*)d_in[21];
    const float* Wv1 = (const float*)d_in[22]; const float* bv1 = (const float*)d_in[23];
    const float* Wp0 = (const float*)d_in[24]; const float* bp0 = (const float*)d_in[25];
    const float* Wp1 = (const float*)d_in[26]; const float* bp1 = (const float*)d_in[27];
    const float* Wd0 = (const float*)d_in[28]; const float* bd0 = (const float*)d_in[29];
    const float* Wd1 = (const float*)d_in[30]; const float* bd1 = (const float*)d_in[31];
    const float* Wd2 = (const float*)d_in[32]; const float* bd2 = (const float*)d_in[33];

    float* partial = (float*)d_ws;   // [256,19] floats = 19456 B

    pair_kernel<<<256, 256, 0, stream>>>(h_v, coords, Wk, bk, Wq, bq,
                                         Wv0, bv0, Wv1, bv1, Wp0, bp0, Wp1,
                                         partial);
    mol_kernel<<<32, 512, 0, stream>>>(hvh, heh, hah, huh,
                                       Wd0, bd0, Wd1, bd1, Wd2, bd2,
                                       Wp1, bp1, bp0, partial, (float*)d_out);
}

// Round 5
// 21.632 us; speedup vs baseline: 2.6913x; 1.0825x over previous
//
#include <hip/hip_runtime.h>
#include <math.h>

// N=1024 atoms, M=32 mols, NB=1024 bonds, NA=1536 angles, T=6, U=32
// atom->mol e/32 (32/mol), bond->mol e/32, angle->mol e/48; torsion unused.
// Masked pairs/mol: 32*(1024-32)=31744; real pairs: 1024/mol.
// s_pair = SK[i] + SQ[j] + elu(d*Wv0+bv0)@W2 + cb
//   SK=(h@Wk+bk)@Wp0_k, SQ=(h@Wq+bq)@Wp0_q, W2=Wv1@Wp0_v, cb=bv1@Wp0_v+bp0
// h_pair[mol] = (sum over pairs of sigmoid(s)) @ Wp1  (+ 32768*bp1 + 31744*sigmoid(bp0)@Wp1)
// Single fused kernel: blocks 0..31 = mol-MLP branch, 32..287 = pair branch.
// Both atomicAdd into d_out (zeroed by hipMemsetAsync).

__device__ __forceinline__ float sigmoidf_(float x) { return 1.0f / (1.0f + __expf(-x)); }

__global__ __launch_bounds__(256) void fused_kernel(
    const float* __restrict__ h_v,      // [1024,32]
    const float* __restrict__ coords,   // [1024,3]
    const float* __restrict__ Wk, const float* __restrict__ bk,
    const float* __restrict__ Wq, const float* __restrict__ bq,
    const float* __restrict__ Wv0, const float* __restrict__ bv0,   // [32],[32]
    const float* __restrict__ Wv1, const float* __restrict__ bv1,   // [32,32],[32]
    const float* __restrict__ Wp0, const float* __restrict__ bp0,   // [96,32],[32]
    const float* __restrict__ Wp1, const float* __restrict__ bp1,   // [32,19],[19]
    const float* __restrict__ hvh,   // [1024,192]
    const float* __restrict__ heh,   // [1024,192]
    const float* __restrict__ hah,   // [1536,192]
    const float* __restrict__ huh,   // [32,192]
    const float* __restrict__ Wd0, const float* __restrict__ bd0,  // [960,64]
    const float* __restrict__ Wd1, const float* __restrict__ bd1,  // [64,64]
    const float* __restrict__ Wd2, const float* __restrict__ bd2,  // [64,19]
    float* __restrict__ out)         // [32,19], pre-zeroed
{
    __shared__ float SH[3072];          // overlay region (see per-branch maps)
    __shared__ float Ql[32 * 36];       // pad 36: 16B-aligned, conflict-free
    __shared__ float Kl[4 * 36];        // only the 4 K-rows this block needs
    __shared__ float wv1l[1024];
    __shared__ float wp0l[3072];
    __shared__ float wp1l[608];
    __shared__ float cbl[32], wv0l[32], bv0l[32];
    __shared__ float cxl[32], cyl[32], czl[32];
    __shared__ float Gl[4 * 32];
    __shared__ float Gs[32];

    const int tid = threadIdx.x;
    const int b = blockIdx.x;

    if (b < 32) {
        // ================= mol-MLP branch =================
        // SH map: x[960] @0, hp[256] @960, h0[64] @1216, h1[64] @1280
        float* x  = SH;
        float* hp = SH + 960;
        float* h0 = SH + 1216;
        float* h1 = SH + 1280;
        const int m = b;

        if (tid < 192) {
            float sv = 0.0f, se = 0.0f, sa = 0.0f;
            const float* pv = hvh + (size_t)(m * 32) * 192 + tid;
            const float* pe = heh + (size_t)(m * 32) * 192 + tid;
            const float* pa = hah + (size_t)(m * 48) * 192 + tid;
            #pragma unroll 8
            for (int e = 0; e < 32; ++e) sv += pv[e * 192];
            #pragma unroll 8
            for (int e = 0; e < 32; ++e) se += pe[e * 192];
            #pragma unroll 8
            for (int e = 0; e < 48; ++e) sa += pa[e * 192];
            x[tid]       = sv;                 // h_v_bar
            x[192 + tid] = se;                 // h_e_bar
            x[384 + tid] = huh[m * 192 + tid]; // h_u_history
            x[576 + tid] = sa;                 // h_a_bar
            x[768 + tid] = sa;                 // h_a_bar again (per source)
        }
        __syncthreads();

        {   // 960 -> 64, 4-way k-split
            const int o = tid & 63, part = tid >> 6;
            const int k0 = part * 240;
            float ssum = 0.0f;
            #pragma unroll 8
            for (int k = k0; k < k0 + 240; ++k) ssum += x[k] * Wd0[k * 64 + o];
            hp[part * 64 + o] = ssum;
        }
        __syncthreads();
        if (tid < 64)
            h0[tid] = sigmoidf_(hp[tid] + hp[64 + tid] + hp[128 + tid] + hp[192 + tid] + bd0[tid]);
        __syncthreads();
        if (tid < 64) {
            float ssum = bd1[tid];
            #pragma unroll
            for (int k = 0; k < 64; ++k) ssum += h0[k] * Wd1[k * 64 + tid];
            h1[tid] = ssum;
        }
        __syncthreads();
        if (tid < 19) {
            float y = bd2[tid];
            #pragma unroll
            for (int k = 0; k < 64; ++k) y += h1[k] * Wd2[k * 19 + tid];
            // masked pairs: 31744*(sigmoid(bp0)@Wp1); bp1 appears 32768x
            float c0m = 0.0f;
            for (int u = 0; u < 32; ++u) c0m += sigmoidf_(bp0[u]) * Wp1[u * 19 + tid];
            atomicAdd(&out[m * 19 + tid], y + 31744.0f * c0m + 32768.0f * bp1[tid]);
        }
        return;
    }

    // ================= pair branch =================
    const int bb = b - 32;
    const int mol = bb >> 3;
    const int oct = bb & 7;
    const int base = mol * 32;

    // SH map phase 1: hl[1024] @0, wkl[1024] @1024, wql[1024] @2048
    // SH map phase 2+: SQl[1152] @0, W2l[1024] @1152  (barrier-separated)
    float* hl  = SH;
    float* wkl = SH + 1024;
    float* wql = SH + 2048;
    float* SQl = SH;            // stride 36
    float* W2l = SH + 1152;     // stride 32

    // ---- stage ----
    ((float4*)hl)[tid]   = ((const float4*)(h_v + (size_t)base * 32))[tid];
    ((float4*)wkl)[tid]  = ((const float4*)Wk)[tid];
    ((float4*)wql)[tid]  = ((const float4*)Wq)[tid];
    ((float4*)wv1l)[tid] = ((const float4*)Wv1)[tid];
    ((float4*)wp0l)[tid]       = ((const float4*)Wp0)[tid];
    ((float4*)wp0l)[tid + 256] = ((const float4*)Wp0)[tid + 256];
    ((float4*)wp0l)[tid + 512] = ((const float4*)Wp0)[tid + 512];
    for (int i = tid; i < 608; i += 256) wp1l[i] = Wp1[i];
    if (tid < 32) {
        wv0l[tid] = Wv0[tid];
        bv0l[tid] = bv0[tid];
        const int gi = base + tid;
        cxl[tid] = coords[gi * 3 + 0];
        cyl[tid] = coords[gi * 3 + 1];
        czl[tid] = coords[gi * 3 + 2];
    }
    __syncthreads();

    // ---- P1: Q = h@Wq+bq for all 32 rows; K only for rows oct*4..+3 ----
    {
        const int u = tid & 31, g = tid >> 5;
        const int a0 = g * 4;
        float qa[4];
        #pragma unroll
        for (int j = 0; j < 4; ++j) qa[j] = bq[u];
        #pragma unroll
        for (int t4 = 0; t4 < 32; t4 += 4) {
            float4 h0 = *(const float4*)&hl[(a0 + 0) * 32 + t4];
            float4 h1 = *(const float4*)&hl[(a0 + 1) * 32 + t4];
            float4 h2 = *(const float4*)&hl[(a0 + 2) * 32 + t4];
            float4 h3 = *(const float4*)&hl[(a0 + 3) * 32 + t4];
            #pragma unroll
            for (int i = 0; i < 4; ++i) {
                const float wq = wql[(t4 + i) * 32 + u];
                qa[0] += (&h0.x)[i] * wq; qa[1] += (&h1.x)[i] * wq;
                qa[2] += (&h2.x)[i] * wq; qa[3] += (&h3.x)[i] * wq;
            }
        }
        #pragma unroll
        for (int j = 0; j < 4; ++j) Ql[(a0 + j) * 36 + u] = qa[j];

        if (g == oct) {   // only 1 of 8 groups; 3 of 4 waves skip entirely
            float ka[4];
            #pragma unroll
            for (int j = 0; j < 4; ++j) ka[j] = bk[u];
            #pragma unroll
            for (int t4 = 0; t4 < 32; t4 += 4) {
                float4 h0 = *(const float4*)&hl[(a0 + 0) * 32 + t4];
                float4 h1 = *(const float4*)&hl[(a0 + 1) * 32 + t4];
                float4 h2 = *(const float4*)&hl[(a0 + 2) * 32 + t4];
                float4 h3 = *(const float4*)&hl[(a0 + 3) * 32 + t4];
                #pragma unroll
                for (int i = 0; i < 4; ++i) {
                    const float wk = wkl[(t4 + i) * 32 + u];
                    ka[0] += (&h0.x)[i] * wk; ka[1] += (&h1.x)[i] * wk;
                    ka[2] += (&h2.x)[i] * wk; ka[3] += (&h3.x)[i] * wk;
                }
            }
            #pragma unroll
            for (int j = 0; j < 4; ++j) Kl[j * 36 + u] = ka[j];
        }
    }
    __syncthreads();   // hl/wkl/wql dead; SH becomes SQl/W2l

    // ---- P2: SQ = Q@Wp0_q (32 rows), W2 = Wv1@Wp0_v, SK (4 rows) ----
    {
        const int w = tid & 31, g = tid >> 5;
        const int a0 = g * 4;
        float sq[4] = {0, 0, 0, 0}, w2[4] = {0, 0, 0, 0};
        #pragma unroll
        for (int u4 = 0; u4 < 32; u4 += 4) {
            float4 q0 = *(const float4*)&Ql[(a0 + 0) * 36 + u4];
            float4 q1 = *(const float4*)&Ql[(a0 + 1) * 36 + u4];
            float4 q2 = *(const float4*)&Ql[(a0 + 2) * 36 + u4];
            float4 q3 = *(const float4*)&Ql[(a0 + 3) * 36 + u4];
            float4 v0 = *(const float4*)&wv1l[(a0 + 0) * 32 + u4];
            float4 v1 = *(const float4*)&wv1l[(a0 + 1) * 32 + u4];
            float4 v2 = *(const float4*)&wv1l[(a0 + 2) * 32 + u4];
            float4 v3 = *(const float4*)&wv1l[(a0 + 3) * 32 + u4];
            #pragma unroll
            for (int i = 0; i < 4; ++i) {
                const float pq = wp0l[(32 + u4 + i) * 32 + w];
                const float pv = wp0l[(64 + u4 + i) * 32 + w];
                sq[0] += (&q0.x)[i] * pq; sq[1] += (&q1.x)[i] * pq;
                sq[2] += (&q2.x)[i] * pq; sq[3] += (&q3.x)[i] * pq;
                w2[0] += (&v0.x)[i] * pv; w2[1] += (&v1.x)[i] * pv;
                w2[2] += (&v2.x)[i] * pv; w2[3] += (&v3.x)[i] * pv;
            }
        }
        #pragma unroll
        for (int j = 0; j < 4; ++j) {
            SQl[(a0 + j) * 36 + w] = sq[j];
            W2l[(a0 + j) * 32 + w] = w2[j];
        }
        if (g == oct) {
            float sk[4] = {0, 0, 0, 0};
            #pragma unroll
            for (int u4 = 0; u4 < 32; u4 += 4) {
                float4 k0 = *(const float4*)&Kl[0 * 36 + u4];
                float4 k1 = *(const float4*)&Kl[1 * 36 + u4];
                float4 k2 = *(const float4*)&Kl[2 * 36 + u4];
                float4 k3 = *(const float4*)&Kl[3 * 36 + u4];
                #pragma unroll
                for (int i = 0; i < 4; ++i) {
                    const float pk = wp0l[(u4 + i) * 32 + w];
                    sk[0] += (&k0.x)[i] * pk; sk[1] += (&k1.x)[i] * pk;
                    sk[2] += (&k2.x)[i] * pk; sk[3] += (&k3.x)[i] * pk;
                }
            }
            // Kl rows no longer needed after this barrier region; but SKl
            // must not alias Kl until all reads done -> write after reads.
            #pragma unroll
            for (int j = 0; j < 4; ++j) Kl[j * 36 + w] = sk[j];  // reuse as SKl
        }
    }
    if (tid < 32) {
        float s = bp0[tid];
        #pragma unroll
        for (int u = 0; u < 32; ++u) s += bv1[u] * wp0l[(64 + u) * 32 + tid];
        cbl[tid] = s;
    }
    __syncthreads();

    // ---- P3: 128 pairs; 4 threads/pair x 8 ch, 2 pairs/thread (same il) ----
    const int ps = tid >> 2, sub = tid & 3;
    const int p0 = oct * 128 + ps * 2;
    const int il = p0 >> 5;              // local atom row (K side)
    const int lil = ps >> 4;             // row within Kl/SKl (0..3)
    const int jl0 = p0 & 31, jl1 = jl0 + 1;

    const float cix = cxl[il], ciy = cyl[il], ciz = czl[il];
    const float dx0 = cix - cxl[jl0], dy0 = ciy - cyl[jl0], dz0 = ciz - czl[jl0];
    const float dx1 = cix - cxl[jl1], dy1 = ciy - cyl[jl1], dz1 = ciz - czl[jl1];
    const float dist0 = sqrtf(fmaxf(dx0 * dx0 + dy0 * dy0 + dz0 * dz0, 1e-12f));
    const float dist1 = sqrtf(fmaxf(dx1 * dx1 + dy1 * dy1 + dz1 * dz1, 1e-12f));

    float e0[32], e1[32];
    #pragma unroll
    for (int t = 0; t < 32; ++t) {
        const float x0 = dist0 * wv0l[t] + bv0l[t];
        const float x1 = dist1 * wv0l[t] + bv0l[t];
        e0[t] = (x0 > 0.0f) ? x0 : (__expf(x0) - 1.0f);
        e1[t] = (x1 > 0.0f) ? x1 : (__expf(x1) - 1.0f);
    }

    float s0[8], s1[8];
    {
        const float4 ska = *(const float4*)&Kl[lil * 36 + sub * 8];      // SKl
        const float4 skb = *(const float4*)&Kl[lil * 36 + sub * 8 + 4];
        const float4 cba = *(const float4*)&cbl[sub * 8];
        const float4 cbb = *(const float4*)&cbl[sub * 8 + 4];
        const float4 q0a = *(const float4*)&SQl[jl0 * 36 + sub * 8];
        const float4 q0b = *(const float4*)&SQl[jl0 * 36 + sub * 8 + 4];
        const float4 q1a = *(const float4*)&SQl[jl1 * 36 + sub * 8];
        const float4 q1b = *(const float4*)&SQl[jl1 * 36 + sub * 8 + 4];
        #pragma unroll
        for (int i = 0; i < 4; ++i) {
            s0[i]     = (&ska.x)[i] + (&q0a.x)[i] + (&cba.x)[i];
            s0[i + 4] = (&skb.x)[i] + (&q0b.x)[i] + (&cbb.x)[i];
            s1[i]     = (&ska.x)[i] + (&q1a.x)[i] + (&cba.x)[i];
            s1[i + 4] = (&skb.x)[i] + (&q1b.x)[i] + (&cbb.x)[i];
        }
    }
    #pragma unroll
    for (int t = 0; t < 32; ++t) {
        const float4 wa = *(const float4*)&W2l[t * 32 + sub * 8];
        const float4 wb = *(const float4*)&W2l[t * 32 + sub * 8 + 4];
        const float a0 = e0[t], a1 = e1[t];
        #pragma unroll
        for (int i = 0; i < 4; ++i) {
            s0[i]     += a0 * (&wa.x)[i];
            s0[i + 4] += a0 * (&wb.x)[i];
            s1[i]     += a1 * (&wa.x)[i];
            s1[i + 4] += a1 * (&wb.x)[i];
        }
    }

    float g[8];
    #pragma unroll
    for (int k = 0; k < 8; ++k) g[k] = sigmoidf_(s0[k]) + sigmoidf_(s1[k]);
    #pragma unroll
    for (int k = 0; k < 8; ++k) {
        g[k] += __shfl_xor(g[k], 4);
        g[k] += __shfl_xor(g[k], 8);
        g[k] += __shfl_xor(g[k], 16);
        g[k] += __shfl_xor(g[k], 32);
    }
    const int lane = tid & 63, wid = tid >> 6;
    if (lane < 4) {
        #pragma unroll
        for (int k = 0; k < 8; ++k) Gl[wid * 32 + sub * 8 + k] = g[k];
    }
    __syncthreads();
    if (tid < 32) Gs[tid] = Gl[tid] + Gl[32 + tid] + Gl[64 + tid] + Gl[96 + tid];
    __syncthreads();
    if (tid < 19) {
        float r = 0.0f;
        #pragma unroll
        for (int u = 0; u < 32; ++u) r += Gs[u] * wp1l[u * 19 + tid];
        atomicAdd(&out[mol * 19 + tid], r);
    }
}

extern "C" void kernel_launch(void* const* d_in, const int* in_sizes, int n_in,
                              void* d_out, int out_size, void* d_ws, size_t ws_size,
                              hipStream_t stream) {
    (void)in_sizes; (void)n_in; (void)d_ws; (void)ws_size;
    const float* h_v    = (const float*)d_in[0];
    const float* hvh    = (const float*)d_in[5];
    const float* heh    = (const float*)d_in[6];
    const float* hah    = (const float*)d_in[7];
    const float* huh    = (const float*)d_in[9];
    const float* coords = (const float*)d_in[15];
    const float* Wk  = (const float*)d_in[16]; const float* bk  = (const float*)d_in[17];
    const float* Wq  = (const float*)d_in[18]; const float* bq  = (const float*)d_in[19];
    const float* Wv0 = (const float*)d_in[20]; const float* bv0 = (const float*)d_in[21];
    const float* Wv1 = (const float*)d_in[22]; const float* bv1 = (const float*)d_in[23];
    const float* Wp0 = (const float*)d_in[24]; const float* bp0 = (const float*)d_in[25];
    const float* Wp1 = (const float*)d_in[26]; const float* bp1 = (const float*)d_in[27];
    const float* Wd0 = (const float*)d_in[28]; const float* bd0 = (const float*)d_in[29];
    const float* Wd1 = (const float*)d_in[30]; const float* bd1 = (const float*)d_in[31];
    const float* Wd2 = (const float*)d_in[32]; const float* bd2 = (const float*)d_in[33];

    hipMemsetAsync(d_out, 0, (size_t)out_size * sizeof(float), stream);
    fused_kernel<<<288, 256, 0, stream>>>(h_v, coords, Wk, bk, Wq, bq,
                                          Wv0, bv0, Wv1, bv1, Wp0, bp0, Wp1, bp1,
                                          hvh, heh, hah, huh,
                                          Wd0, bd0, Wd1, bd1, Wd2, bd2,
                                          (float*)d_out);
}